// Round 7
// baseline (720.247 us; speedup 1.0000x reference)
//
#include <hip/hip_runtime.h>
#include <math.h>

#define LL 4096
#define NB 64
#define WW 64
#define NMODES 32
#define NCIN 24
#define NLAY 4
#define NPROJ 128
#define NSTC 16
#define NSPLIT 16

typedef __attribute__((ext_vector_type(8))) short short8;
typedef __attribute__((ext_vector_type(4))) float f32x4;

// gelu(tanh approx) = x * sigmoid(2u), u = c0*(x + c1*x^3)  [exact identity]
static __device__ __forceinline__ float gelu_fast(float x){
    const float c0 = 0.7978845608028654f;
    const float c1 = 0.044715f;
    float u = c0*(x + c1*x*x*x);
    return x / (1.0f + __expf(-2.0f*u));
}

static __device__ __forceinline__ unsigned short bf16_rn(float v){
    unsigned int u = __float_as_uint(v);
    unsigned int r = (u + 0x7fffu + ((u>>16)&1u)) >> 16;
    return (unsigned short)r;
}
static __device__ __forceinline__ float bf16f(unsigned short h){
    return __uint_as_float(((unsigned int)h)<<16);
}
static __device__ __forceinline__ void split_store(unsigned short* hi, unsigned short* lo,
                                                   size_t idx, float v){
    unsigned short h = bf16_rn(v);
    hi[idx] = h;
    lo[idx] = bf16_rn(v - bf16f(h));
}

// ---------------- tables ----------------
// TD[n][x] (x-fast): n<32 cos, n>=32 -sin  (forward DFT basis)
// TIk[x][m] (mode-fast, transposed): irfft-scaled; col 32 (Im bin0) = 0.
__global__ void k_tables(unsigned short* __restrict__ TD_hi, unsigned short* __restrict__ TD_lo,
                         unsigned short* __restrict__ TIk_hi, unsigned short* __restrict__ TIk_lo){
    int idx = blockIdx.x*256 + threadIdx.x;
    if (idx >= LL*NMODES) return;
    int x = idx & (LL-1);
    int k = idx >> 12;
    int ph = (k*x) & (LL-1);                 // exact integer phase mod L
    float ang = (6.283185307179586f/(float)LL)*(float)ph;
    float c = cosf(ang), s = sinf(ang);
    split_store(TD_hi, TD_lo, (size_t)k*LL + x, c);
    split_store(TD_hi, TD_lo, (size_t)(k+NMODES)*LL + x, -s);
    float tc, ts;
    if (k == 0){ tc = 1.0f/(float)LL; ts = 0.0f; }
    else { tc = (2.0f/(float)LL)*c; ts = -(2.0f/(float)LL)*s; }
    split_store(TIk_hi, TIk_lo, (size_t)x*64 + k, tc);
    split_store(TIk_hi, TIk_lo, (size_t)x*64 + NMODES + k, ts);
}

// ---------------- weight prep: wrT/wiT fp32 [l][m][i][o]; skwT bf16 [l][o][i] ----------------
__global__ void k_wt(const float* __restrict__ wr, const float* __restrict__ wi,
                     float* __restrict__ wrT, float* __restrict__ wiT,
                     const float* __restrict__ skw,
                     unsigned short* __restrict__ skwT_hi, unsigned short* __restrict__ skwT_lo){
    int idx = blockIdx.x*256 + threadIdx.x;
    if (idx < NLAY*WW*WW*NMODES){
        int m = idx & 31;
        int o = (idx >> 5) & 63;
        int i = (idx >> 11) & 63;
        int l = idx >> 17;
        size_t dst = (((size_t)l*NMODES + m)*WW + i)*WW + o;
        wrT[dst] = wr[idx];
        wiT[dst] = wi[idx];
    }
    if (idx < NLAY*WW*WW){
        int o = idx & 63;
        int i = (idx >> 6) & 63;
        int l = idx >> 12;
        float v = skw[((size_t)l*WW + i)*WW + o];
        split_store(skwT_hi, skwT_lo, ((size_t)l*WW + o)*WW + i, v);
    }
}

// ---------------- lifting -> hT[b][x][ch] planes (channel-fast, vectorized stores) ----------------
__global__ void k_lift(const float* __restrict__ u, const float* __restrict__ z,
                       const float* __restrict__ w0, const float* __restrict__ b0,
                       unsigned short* __restrict__ hT_hi, unsigned short* __restrict__ hT_lo){
    __shared__ float Ws[NCIN*WW];
    __shared__ float Bs[WW];
    __shared__ float Zs[16];
    int b = blockIdx.y;
    int x0 = blockIdx.x*256;
    int tid = threadIdx.x;
    for (int i = tid; i < NCIN*WW; i += 256) Ws[i] = w0[i];
    if (tid < WW) Bs[tid] = b0[tid];
    if (tid < 16) Zs[tid] = z[b*16 + tid];
    __syncthreads();
    int x = x0 + tid;
    const float4* up = (const float4*)(u + ((size_t)b*LL + x)*8);
    float4 a0 = up[0], a1 = up[1];
    float ur[8] = {a0.x,a0.y,a0.z,a0.w,a1.x,a1.y,a1.z,a1.w};
    float zr[16];
    #pragma unroll
    for (int j=0;j<16;j++) zr[j] = Zs[j];
    size_t rowbase = ((size_t)b*LL + x)*64;
    for (int c0=0;c0<WW;c0+=4){
        unsigned long long hv = 0ull, lv = 0ull;
        #pragma unroll
        for (int r=0;r<4;r++){
            int c = c0 + r;
            float acc = Bs[c];
            #pragma unroll
            for (int j=0;j<8;j++)  acc += ur[j]*Ws[j*WW+c];
            #pragma unroll
            for (int j=0;j<16;j++) acc += zr[j]*Ws[(8+j)*WW+c];
            unsigned short h16 = bf16_rn(acc);
            unsigned short l16 = bf16_rn(acc - bf16f(h16));
            hv |= ((unsigned long long)h16) << (16*r);
            lv |= ((unsigned long long)l16) << (16*r);
        }
        *(unsigned long long*)(hT_hi + rowbase + c0) = hv;
        *(unsigned long long*)(hT_lo + rowbase + c0) = lv;
    }
}

// ---------------- truncated DFT: register-only split-bf16 MFMA, split-K ----------------
// part[s][b*64+ch][n] = sum_{x in split s} hT[b][x][ch]*TD[n][x]
// grid (64 b, 16 splits), 256 threads (4 waves). A = h (8-elem x-gather), B = TD (vector).
__global__ __launch_bounds__(256) void k_dft(
        const unsigned short* __restrict__ hT_hi, const unsigned short* __restrict__ hT_lo,
        const unsigned short* __restrict__ td_hi, const unsigned short* __restrict__ td_lo,
        float* __restrict__ part){
    int rt = blockIdx.x;
    int s  = blockIdx.y;
    int tid = threadIdx.x;
    int w = tid >> 6;
    int lane = tid & 63;
    int g = lane >> 4;       // k-group
    int i = lane & 15;       // A-row(ch) / B-col(n) index
    f32x4 acc[4];
    #pragma unroll
    for (int nf=0;nf<4;nf++) acc[nf] = (f32x4){0.f,0.f,0.f,0.f};
    int ch = w*16 + i;
    size_t bbase = (size_t)rt*LL;
    int xbase = s*256;
    for (int ks=0; ks<8; ks++){
        int xk = xbase + ks*32 + g*8;
        short8 a_hi, a_lo;
        size_t idx0 = (bbase + xk)*64 + ch;
        #pragma unroll
        for (int e=0;e<8;e++){
            a_hi[e] = (short)hT_hi[idx0 + (size_t)e*64];
            a_lo[e] = (short)hT_lo[idx0 + (size_t)e*64];
        }
        #pragma unroll
        for (int nf=0;nf<4;nf++){
            size_t brow = (size_t)(nf*16 + i)*LL + xk;
            short8 b_hi = *(const short8*)(td_hi + brow);
            short8 b_lo = *(const short8*)(td_lo + brow);
            acc[nf] = __builtin_amdgcn_mfma_f32_16x16x32_bf16(a_lo, b_hi, acc[nf], 0,0,0);
            acc[nf] = __builtin_amdgcn_mfma_f32_16x16x32_bf16(a_hi, b_lo, acc[nf], 0,0,0);
            acc[nf] = __builtin_amdgcn_mfma_f32_16x16x32_bf16(a_hi, b_hi, acc[nf], 0,0,0);
        }
    }
    // D: row=(lane>>4)*4+r (ch-space), col=lane&15 (n-space)
    int drow = rt*64 + w*16 + g*4;
    #pragma unroll
    for (int nf=0;nf<4;nf++)
        #pragma unroll
        for (int r=0;r<4;r++)
            part[((size_t)s*4096 + drow + r)*64 + nf*16 + i] = acc[nf][r];
}

// ---------------- reduce partials -> hfT[b][m][{re,im}][i] (fp32) ----------------
__global__ void k_reduce(const float* __restrict__ part, float* __restrict__ hfT){
    int e = blockIdx.x*256 + threadIdx.x;       // < 64*32*128
    int i    = e & 63;
    int reim = (e >> 6) & 1;
    int m    = (e >> 7) & 31;
    int b    = e >> 12;
    int n = m + 32*reim;
    size_t rowoff = ((size_t)b*WW + i)*64 + n;
    float s = 0.f;
    #pragma unroll
    for (int sp=0; sp<NSPLIT; sp++) s += part[(size_t)sp*262144 + rowoff];
    hfT[e] = s;
}

// ---------------- mode mix -> of fp32 [b][o][64] + bf16 planes ----------------
__global__ void k_mix(const float* __restrict__ hfT, const float* __restrict__ wrT,
                      const float* __restrict__ wiT, float* __restrict__ of,
                      unsigned short* __restrict__ of_hi, unsigned short* __restrict__ of_lo){
    int m = blockIdx.x, b = blockIdx.y;
    int o = threadIdx.x;
    __shared__ float hr[64], hi_[64];
    const float* row = hfT + ((size_t)b*NMODES + m)*128;
    hr[o] = row[o];
    hi_[o] = row[64+o];
    __syncthreads();
    float ar = 0.f, ai = 0.f;
    const float* wr = wrT + (size_t)m*4096;   // [i][o]
    const float* wi = wiT + (size_t)m*4096;
    for (int i=0;i<64;i++){
        float wrv = wr[i*64+o], wiv = wi[i*64+o];
        float r = hr[i], im = hi_[i];
        ar += r*wrv - im*wiv;
        ai += r*wiv + im*wrv;
    }
    size_t base = ((size_t)b*WW+o)*64;
    of[base + m]      = ar;
    of[base + 32 + m] = ai;
    split_store(of_hi, of_lo, base + m, ar);
    split_store(of_hi, of_lo, base + 32 + m, ai);
}

// ---------------- fused iDFT + skip + bias + gelu: no LDS, no barriers ----------------
// out[o][x] = sum_{ch} skwT[o][ch]*hT[b][x][ch] + sum_m of[b][o][m]*TIk[x][m] + skb[o]
// grid (64 x-tiles, 64 b), 256 threads (4 waves). M=o, N=x, K=128 (64 ch + 64 modes).
__global__ __launch_bounds__(256) void k_fused(
        const unsigned short* __restrict__ hT_hi, const unsigned short* __restrict__ hT_lo,
        const unsigned short* __restrict__ tik_hi, const unsigned short* __restrict__ tik_lo,
        const unsigned short* __restrict__ skwT_hi, const unsigned short* __restrict__ skwT_lo,
        const unsigned short* __restrict__ of_hi, const unsigned short* __restrict__ of_lo,
        const float* __restrict__ skb,
        unsigned short* __restrict__ hoT_hi, unsigned short* __restrict__ hoT_lo){
    int b  = blockIdx.y;
    int X0 = blockIdx.x*64;
    int tid = threadIdx.x;
    int w = tid >> 6, lane = tid & 63, g = lane >> 4, j = lane & 15;
    int xrow = X0 + w*16 + j;
    size_t xb = ((size_t)b*LL + xrow)*64;    // hT row base
    size_t tb = (size_t)xrow*64;             // TIk row base
    f32x4 acc[4];
    #pragma unroll
    for (int mf=0; mf<4; mf++) acc[mf] = (f32x4){0.f,0.f,0.f,0.f};
    #pragma unroll
    for (int ks=0; ks<4; ks++){
        int ko = ks*32 + g*8;
        const unsigned short* bp_hi = (ks < 2) ? (hT_hi + xb + ko) : (tik_hi + tb + ko - 64);
        const unsigned short* bp_lo = (ks < 2) ? (hT_lo + xb + ko) : (tik_lo + tb + ko - 64);
        short8 bh = *(const short8*)bp_hi;
        short8 bl = *(const short8*)bp_lo;
        #pragma unroll
        for (int mf=0; mf<4; mf++){
            int o = mf*16 + j;
            const unsigned short *pa_hi, *pa_lo;
            if (ks < 2){
                pa_hi = skwT_hi + (o<<6) + ko;
                pa_lo = skwT_lo + (o<<6) + ko;
            } else {
                size_t bo = ((size_t)(b*64 + o))<<6;
                pa_hi = of_hi + bo + ko - 64;
                pa_lo = of_lo + bo + ko - 64;
            }
            short8 ah = *(const short8*)pa_hi;
            short8 al = *(const short8*)pa_lo;
            acc[mf] = __builtin_amdgcn_mfma_f32_16x16x32_bf16(al, bh, acc[mf], 0,0,0);
            acc[mf] = __builtin_amdgcn_mfma_f32_16x16x32_bf16(ah, bl, acc[mf], 0,0,0);
            acc[mf] = __builtin_amdgcn_mfma_f32_16x16x32_bf16(ah, bh, acc[mf], 0,0,0);
        }
    }
    // epilogue: D lane (g,j): col x=j(xrow), rows o=mf*16+g*4+r -> contiguous 4-ch packs
    #pragma unroll
    for (int mf=0; mf<4; mf++){
        unsigned long long hv = 0ull, lv = 0ull;
        #pragma unroll
        for (int r=0; r<4; r++){
            int o = mf*16 + g*4 + r;
            float v = acc[mf][r] + skb[o];
            v = gelu_fast(v);
            unsigned short h16 = bf16_rn(v);
            unsigned short l16 = bf16_rn(v - bf16f(h16));
            hv |= ((unsigned long long)h16) << (16*r);
            lv |= ((unsigned long long)l16) << (16*r);
        }
        *(unsigned long long*)(hoT_hi + xb + mf*16 + g*4) = hv;
        *(unsigned long long*)(hoT_lo + xb + mf*16 + g*4) = lv;
    }
}

// ---------------- final: layer-3 tail at x=L-1 + projection ----------------
__global__ void k_final(const unsigned short* __restrict__ h3T_hi,
                        const unsigned short* __restrict__ h3T_lo,
                        const float* __restrict__ of,
                        const float* __restrict__ skw, const float* __restrict__ skb,
                        const unsigned short* __restrict__ tik_hi,
                        const unsigned short* __restrict__ tik_lo,
                        const float* __restrict__ w1, const float* __restrict__ b1,
                        const float* __restrict__ w2, const float* __restrict__ b2,
                        float* __restrict__ out){
    int b = blockIdx.x;
    int tid = threadIdx.x;  // 128
    __shared__ float hch[64];
    __shared__ float til[64];
    __shared__ float hv[64];
    __shared__ float qv[128];
    if (tid < 64){
        size_t idx = ((size_t)b*LL + (LL-1))*64 + tid;
        hch[tid] = bf16f(h3T_hi[idx]) + bf16f(h3T_lo[idx]);
    } else {
        size_t idx = (size_t)(LL-1)*64 + (tid-64);
        til[tid-64] = bf16f(tik_hi[idx]) + bf16f(tik_lo[idx]);
    }
    __syncthreads();
    if (tid < 64){
        int o = tid;
        float acc = skb[o];
        const float* ofr = of + ((size_t)b*WW + o)*64;
        #pragma unroll
        for (int j=0;j<64;j++) acc += ofr[j]*til[j];
        #pragma unroll
        for (int i=0;i<64;i++) acc += hch[i]*skw[i*64+o];
        hv[o] = acc;                       // last layer: no gelu
    }
    __syncthreads();
    {
        int p = tid;
        float acc = b1[p];
        for (int o=0;o<64;o++) acc += hv[o]*w1[o*NPROJ+p];
        qv[p] = gelu_fast(acc);
    }
    __syncthreads();
    if (tid < NSTC){
        int s = tid;
        float acc = b2[s];
        for (int p=0;p<NPROJ;p++) acc += qv[p]*w2[p*NSTC+s];
        out[b*NSTC + s] = acc;
    }
}

extern "C" void kernel_launch(void* const* d_in, const int* in_sizes, int n_in,
                              void* d_out, int out_size, void* d_ws, size_t ws_size,
                              hipStream_t stream) {
    const float* u     = (const float*)d_in[0];
    const float* z     = (const float*)d_in[1];
    // d_in[2] = t, unused by reference
    const float* fc0w  = (const float*)d_in[3];
    const float* fc0b  = (const float*)d_in[4];
    const float* swr   = (const float*)d_in[5];
    const float* swi   = (const float*)d_in[6];
    const float* skw   = (const float*)d_in[7];
    const float* skb   = (const float*)d_in[8];
    const float* fc1w  = (const float*)d_in[9];
    const float* fc1b  = (const float*)d_in[10];
    const float* fc2w  = (const float*)d_in[11];
    const float* fc2b  = (const float*)d_in[12];
    float* out = (float*)d_out;

    const size_t SZ_HP   = (size_t)NB*LL*64*2;          // 32 MiB per hT plane
    const size_t SZ_TBL  = (size_t)64*LL*2;             // 512 KiB per table plane
    const size_t SZ_HFT  = (size_t)64*32*128*4;         // 1 MiB
    const size_t SZ_OF   = (size_t)64*64*64*4;          // 1 MiB fp32
    const size_t SZ_OFP  = (size_t)64*64*64*2;          // 512 KiB per of plane
    const size_t SZ_WT   = (size_t)NLAY*NMODES*WW*WW*4; // 2 MiB
    const size_t SZ_SKT  = (size_t)NLAY*WW*WW*2;        // 32 KiB per skwT plane

    size_t need = 4*SZ_HP + 4*SZ_TBL + SZ_HFT + SZ_OF + 2*SZ_OFP + 2*SZ_WT + 2*SZ_SKT;
    if (ws_size < need) return;

    char* p = (char*)d_ws;
    unsigned short* hAT_hi = (unsigned short*)p; p += SZ_HP;
    unsigned short* hAT_lo = (unsigned short*)p; p += SZ_HP;
    unsigned short* hBT_hi = (unsigned short*)p; p += SZ_HP;
    unsigned short* hBT_lo = (unsigned short*)p; p += SZ_HP;
    unsigned short* TD_hi  = (unsigned short*)p; p += SZ_TBL;
    unsigned short* TD_lo  = (unsigned short*)p; p += SZ_TBL;
    unsigned short* TIk_hi = (unsigned short*)p; p += SZ_TBL;
    unsigned short* TIk_lo = (unsigned short*)p; p += SZ_TBL;
    float* hfT   = (float*)p; p += SZ_HFT;
    float* of    = (float*)p; p += SZ_OF;
    unsigned short* of_hi = (unsigned short*)p; p += SZ_OFP;
    unsigned short* of_lo = (unsigned short*)p; p += SZ_OFP;
    float* wrT   = (float*)p; p += SZ_WT;
    float* wiT   = (float*)p; p += SZ_WT;
    unsigned short* skwT_hi = (unsigned short*)p; p += SZ_SKT;
    unsigned short* skwT_lo = (unsigned short*)p; p += SZ_SKT;

    k_tables<<<(LL*NMODES+255)/256, 256, 0, stream>>>(TD_hi, TD_lo, TIk_hi, TIk_lo);
    k_wt<<<(NLAY*WW*WW*NMODES+255)/256, 256, 0, stream>>>(swr, swi, wrT, wiT,
                                                          skw, skwT_hi, skwT_lo);
    k_lift<<<dim3(LL/256, NB), 256, 0, stream>>>(u, z, fc0w, fc0b, hAT_hi, hAT_lo);

    unsigned short* cur_hi = hAT_hi; unsigned short* cur_lo = hAT_lo;
    unsigned short* nxt_hi = hBT_hi; unsigned short* nxt_lo = hBT_lo;
    for (int l = 0; l < NLAY; l++){
        // part (16 MiB) aliases the dead destination plane (32 MiB)
        float* part = (float*)nxt_hi;
        k_dft<<<dim3(NB, NSPLIT), 256, 0, stream>>>(cur_hi, cur_lo, TD_hi, TD_lo, part);
        k_reduce<<<(64*32*128)/256, 256, 0, stream>>>(part, hfT);
        k_mix<<<dim3(NMODES, NB), 64, 0, stream>>>(hfT, wrT + (size_t)l*NMODES*WW*WW,
                                                   wiT + (size_t)l*NMODES*WW*WW,
                                                   of, of_hi, of_lo);
        if (l < NLAY-1){
            k_fused<<<dim3(LL/64, NB), 256, 0, stream>>>(cur_hi, cur_lo, TIk_hi, TIk_lo,
                skwT_hi + (size_t)l*WW*WW, skwT_lo + (size_t)l*WW*WW,
                of_hi, of_lo, skb + (size_t)l*WW, nxt_hi, nxt_lo);
            unsigned short* t;
            t = cur_hi; cur_hi = nxt_hi; nxt_hi = t;
            t = cur_lo; cur_lo = nxt_lo; nxt_lo = t;
        }
    }
    k_final<<<NB, 128, 0, stream>>>(cur_hi, cur_lo, of, skw + (size_t)3*WW*WW,
                                    skb + (size_t)3*WW, TIk_hi, TIk_lo,
                                    fc1w, fc1b, fc2w, fc2b, out);
}

// Round 8
// 635.689 us; speedup vs baseline: 1.1330x; 1.1330x over previous
//
#include <hip/hip_runtime.h>
#include <math.h>

#define LL 4096
#define NB 64
#define WW 64
#define NMODES 32
#define NCIN 24
#define NLAY 4
#define NPROJ 128
#define NSTC 16
#define NSPLIT 16

typedef __attribute__((ext_vector_type(8))) short short8;
typedef __attribute__((ext_vector_type(4))) float f32x4;

typedef const __attribute__((address_space(1))) unsigned int* gas_ptr;
typedef __attribute__((address_space(3))) unsigned int* las_ptr;

static __device__ __forceinline__ void gload16(const unsigned int* g, unsigned int* l){
    __builtin_amdgcn_global_load_lds((gas_ptr)g, (las_ptr)l, 16, 0, 0);
}

// gelu(tanh approx) = x * sigmoid(2u), u = c0*(x + c1*x^3)  [exact identity]
static __device__ __forceinline__ float gelu_fast(float x){
    const float c0 = 0.7978845608028654f;
    const float c1 = 0.044715f;
    float u = c0*(x + c1*x*x*x);
    return x / (1.0f + __expf(-2.0f*u));
}

static __device__ __forceinline__ unsigned short bf16_rn(float v){
    unsigned int u = __float_as_uint(v);
    unsigned int r = (u + 0x7fffu + ((u>>16)&1u)) >> 16;
    return (unsigned short)r;
}
static __device__ __forceinline__ float bf16f(unsigned short h){
    return __uint_as_float(((unsigned int)h)<<16);
}
// packed split element: low16 = hi bf16, high16 = lo (residual) bf16
static __device__ __forceinline__ unsigned int pack_split(float v){
    unsigned short h = bf16_rn(v);
    unsigned short l = bf16_rn(v - bf16f(h));
    return (unsigned int)h | ((unsigned int)l<<16);
}
static __device__ __forceinline__ float unpack_sum(unsigned int w){
    return bf16f((unsigned short)(w & 0xffffu)) + bf16f((unsigned short)(w >> 16));
}
// 8 packed u32 -> hi-plane short8 / lo-plane short8
static __device__ __forceinline__ short8 hi8(uint4 a, uint4 b){
    union { unsigned int u[4]; short8 s; } r;
    r.u[0] = (a.x & 0xffffu) | (a.y << 16);
    r.u[1] = (a.z & 0xffffu) | (a.w << 16);
    r.u[2] = (b.x & 0xffffu) | (b.y << 16);
    r.u[3] = (b.z & 0xffffu) | (b.w << 16);
    return r.s;
}
static __device__ __forceinline__ short8 lo8(uint4 a, uint4 b){
    union { unsigned int u[4]; short8 s; } r;
    r.u[0] = (a.x >> 16) | (a.y & 0xffff0000u);
    r.u[1] = (a.z >> 16) | (a.w & 0xffff0000u);
    r.u[2] = (b.x >> 16) | (b.y & 0xffff0000u);
    r.u[3] = (b.z >> 16) | (b.w & 0xffff0000u);
    return r.s;
}

// ---------------- tables (packed u32, x-major) ----------------
// TD32[n][x]: n<32 cos, n>=32 -sin. TI32[k][x]: irfft-scaled; row 32 (Im bin0)=0.
__global__ void k_tables(unsigned int* __restrict__ TD32, unsigned int* __restrict__ TI32){
    int idx = blockIdx.x*256 + threadIdx.x;
    if (idx >= LL*NMODES) return;
    int x = idx & (LL-1);
    int k = idx >> 12;
    int ph = (k*x) & (LL-1);                 // exact integer phase mod L
    float ang = (6.283185307179586f/(float)LL)*(float)ph;
    float c = cosf(ang), s = sinf(ang);
    TD32[(size_t)k*LL + x]          = pack_split(c);
    TD32[(size_t)(k+NMODES)*LL + x] = pack_split(-s);
    float tc, ts;
    if (k == 0){ tc = 1.0f/(float)LL; ts = 0.0f; }
    else { tc = (2.0f/(float)LL)*c; ts = -(2.0f/(float)LL)*s; }
    TI32[(size_t)k*LL + x]          = pack_split(tc);
    TI32[(size_t)(k+NMODES)*LL + x] = pack_split(ts);
}

// ---------------- weight prep: wrT/wiT fp32 [l][m][i][o]; skw32 [l][o][64i] packed ----------------
__global__ void k_wt(const float* __restrict__ wr, const float* __restrict__ wi,
                     float* __restrict__ wrT, float* __restrict__ wiT,
                     const float* __restrict__ skw, unsigned int* __restrict__ skw32){
    int idx = blockIdx.x*256 + threadIdx.x;
    if (idx < NLAY*WW*WW*NMODES){
        int m = idx & 31;
        int o = (idx >> 5) & 63;
        int i = (idx >> 11) & 63;
        int l = idx >> 17;
        size_t dst = (((size_t)l*NMODES + m)*WW + i)*WW + o;
        wrT[dst] = wr[idx];
        wiT[dst] = wi[idx];
    }
    if (idx < NLAY*WW*WW){
        int o = idx & 63;
        int i = (idx >> 6) & 63;
        int l = idx >> 12;
        float v = skw[((size_t)l*WW + i)*WW + o];
        skw32[((size_t)l*WW + o)*WW + i] = pack_split(v);
    }
}

// ---------------- lifting -> h32[b][ch][x] (x-major packed) ----------------
__global__ void k_lift(const float* __restrict__ u, const float* __restrict__ z,
                       const float* __restrict__ w0, const float* __restrict__ b0,
                       unsigned int* __restrict__ h32){
    __shared__ float Ws[NCIN*WW];
    __shared__ float Bs[WW];
    __shared__ float Zs[16];
    int b = blockIdx.y;
    int x0 = blockIdx.x*256;
    int tid = threadIdx.x;
    for (int i = tid; i < NCIN*WW; i += 256) Ws[i] = w0[i];
    if (tid < WW) Bs[tid] = b0[tid];
    if (tid < 16) Zs[tid] = z[b*16 + tid];
    __syncthreads();
    int x = x0 + tid;
    const float4* up = (const float4*)(u + ((size_t)b*LL + x)*8);
    float4 a0 = up[0], a1 = up[1];
    float ur[8] = {a0.x,a0.y,a0.z,a0.w,a1.x,a1.y,a1.z,a1.w};
    float zr[16];
    #pragma unroll
    for (int j=0;j<16;j++) zr[j] = Zs[j];
    for (int c=0;c<WW;c++){
        float acc = Bs[c];
        #pragma unroll
        for (int j=0;j<8;j++)  acc += ur[j]*Ws[j*WW+c];
        #pragma unroll
        for (int j=0;j<16;j++) acc += zr[j]*Ws[(8+j)*WW+c];
        h32[((size_t)(b*WW + c))*LL + x] = pack_split(acc);
    }
}

// ---------------- truncated DFT: register MFMA, A fully preloaded ----------------
// part[s][b*64+ch][n] = sum_{x in split s} h[ch][x]*TD[n][x]
// grid (64 b, 16 splits), 256 threads (4 waves), wave w -> ch rows w*16..+15.
__global__ __launch_bounds__(256) void k_dft(
        const unsigned int* __restrict__ h32, const unsigned int* __restrict__ td32,
        float* __restrict__ part){
    int bb = blockIdx.x;
    int s  = blockIdx.y;
    int tid = threadIdx.x;
    int w = tid >> 6;
    int lane = tid & 63;
    int g = lane >> 4;       // k-group
    int i = lane & 15;       // A-row(ch) / B-col(n)
    int ch = w*16 + i;
    size_t abase = ((size_t)(bb*64 + ch))*LL + s*256;
    // preload all A (h) vectors: 16 x uint4 in flight
    uint4 av[16];
    #pragma unroll
    for (int ks=0; ks<8; ks++){
        const uint4* ap = (const uint4*)(h32 + abase + ks*32 + g*8);
        av[2*ks]   = ap[0];
        av[2*ks+1] = ap[1];
    }
    f32x4 acc[4];
    #pragma unroll
    for (int nf=0;nf<4;nf++) acc[nf] = (f32x4){0.f,0.f,0.f,0.f};
    #pragma unroll
    for (int ks=0; ks<8; ks++){
        short8 ah = hi8(av[2*ks], av[2*ks+1]);
        short8 al = lo8(av[2*ks], av[2*ks+1]);
        #pragma unroll
        for (int nf=0;nf<4;nf++){
            const uint4* bp = (const uint4*)(td32 + (size_t)(nf*16 + i)*LL + s*256 + ks*32 + g*8);
            uint4 b0 = bp[0], b1 = bp[1];
            short8 bh = hi8(b0,b1);
            short8 bl = lo8(b0,b1);
            acc[nf] = __builtin_amdgcn_mfma_f32_16x16x32_bf16(al, bh, acc[nf], 0,0,0);
            acc[nf] = __builtin_amdgcn_mfma_f32_16x16x32_bf16(ah, bl, acc[nf], 0,0,0);
            acc[nf] = __builtin_amdgcn_mfma_f32_16x16x32_bf16(ah, bh, acc[nf], 0,0,0);
        }
    }
    // D: row=(lane>>4)*4+r (ch-space), col=lane&15 (n-space)
    int drow = bb*64 + w*16 + g*4;
    #pragma unroll
    for (int nf=0;nf<4;nf++)
        #pragma unroll
        for (int r=0;r<4;r++)
            part[((size_t)s*4096 + drow + r)*64 + nf*16 + i] = acc[nf][r];
}

// ---------------- reduce partials -> hfT[b][m][{re,im}][i] (fp32) ----------------
__global__ void k_reduce(const float* __restrict__ part, float* __restrict__ hfT){
    int e = blockIdx.x*256 + threadIdx.x;       // < 64*32*128
    int i    = e & 63;
    int reim = (e >> 6) & 1;
    int m    = (e >> 7) & 31;
    int b    = e >> 12;
    int n = m + 32*reim;
    size_t rowoff = ((size_t)b*WW + i)*64 + n;
    float s = 0.f;
    #pragma unroll
    for (int sp=0; sp<NSPLIT; sp++) s += part[(size_t)sp*262144 + rowoff];
    hfT[e] = s;
}

// ---------------- mode mix -> of fp32 [b][o][64] + of32 packed ----------------
__global__ void k_mix(const float* __restrict__ hfT, const float* __restrict__ wrT,
                      const float* __restrict__ wiT, float* __restrict__ of,
                      unsigned int* __restrict__ of32){
    int m = blockIdx.x, b = blockIdx.y;
    int o = threadIdx.x;
    __shared__ float hr[64], hi_[64];
    const float* row = hfT + ((size_t)b*NMODES + m)*128;
    hr[o] = row[o];
    hi_[o] = row[64+o];
    __syncthreads();
    float ar = 0.f, ai = 0.f;
    const float* wrp = wrT + (size_t)m*4096;   // [i][o]
    const float* wip = wiT + (size_t)m*4096;
    for (int i=0;i<64;i++){
        float wrv = wrp[i*64+o], wiv = wip[i*64+o];
        float r = hr[i], im = hi_[i];
        ar += r*wrv - im*wiv;
        ai += r*wiv + im*wrv;
    }
    size_t base = ((size_t)b*WW+o)*64;
    of[base + m]      = ar;
    of[base + 32 + m] = ai;
    of32[base + m]      = pack_split(ar);
    of32[base + 32 + m] = pack_split(ai);
}

// ---------------- fused iDFT + skip + bias + gelu: global_load_lds staged ----------------
// out[o][x] = sum_ch skw[o][ch]*h[ch][x] + sum_k of[o][k]*TI[k][x] + skb[o]
// grid (64 x-tiles, 64 b), 256 threads (4 waves). M=o(64), N=x(16/wave), K=128.
// LDS 32 KB: tile[0..4095] = h rows (64ch x 64x u32), tile[4096..] = TI rows.
// Swizzle: phys_x = x ^ (((row>>3)&1)<<4) on BOTH stage-source and read (rule #21).
__global__ __launch_bounds__(256) void k_fused(
        const unsigned int* __restrict__ h32in, const unsigned int* __restrict__ ti32,
        const unsigned int* __restrict__ skw32, const unsigned int* __restrict__ of32,
        const float* __restrict__ skb,
        unsigned int* __restrict__ h32out){
    __shared__ unsigned int tile[2*64*64];
    int b  = blockIdx.y;
    int X0 = blockIdx.x*64;
    int tid = threadIdx.x;
    int w = tid >> 6, lane = tid & 63, g = lane >> 4, j = lane & 15;
    // --- async stage: wave w stages rows w*16..+15 of both tiles (8 issues/wave)
    #pragma unroll
    for (int it=0; it<4; it++){
        int r0 = w*16 + it*4;
        int row = r0 + (lane >> 4);
        int p0 = (lane & 15)*4;
        int sx = ((row >> 3) & 1) << 4;
        gload16(h32in + ((size_t)(b*64 + row))*LL + X0 + (p0 ^ sx), &tile[r0*64]);
        gload16(ti32  + (size_t)row*LL          + X0 + (p0 ^ sx), &tile[4096 + r0*64]);
    }
    __syncthreads();
    // --- MFMA
    f32x4 acc[4];
    #pragma unroll
    for (int mf=0;mf<4;mf++) acc[mf] = (f32x4){0.f,0.f,0.f,0.f};
    int xl = w*16 + j;
    #pragma unroll
    for (int ks=0; ks<4; ks++){
        unsigned int bv[8];
        #pragma unroll
        for (int e=0; e<8; e++){
            int kr = (ks&1)*32 + g*8 + e;          // row within half-tile
            int sx = ((kr >> 3) & 1) << 4;
            bv[e] = tile[(ks>>1)*4096 + kr*64 + (xl ^ sx)];
        }
        uint4 b0 = make_uint4(bv[0],bv[1],bv[2],bv[3]);
        uint4 b1 = make_uint4(bv[4],bv[5],bv[6],bv[7]);
        short8 bh = hi8(b0,b1);
        short8 bl = lo8(b0,b1);
        #pragma unroll
        for (int mf=0; mf<4; mf++){
            int o = mf*16 + j;
            const unsigned int* pa = (ks < 2)
                ? (skw32 + (o<<6) + ks*32 + g*8)
                : (of32 + (((size_t)(b*64 + o))<<6) + (ks&1)*32 + g*8);
            uint4 a0 = *(const uint4*)pa;
            uint4 a1 = *(const uint4*)(pa + 4);
            short8 ah = hi8(a0,a1);
            short8 al = lo8(a0,a1);
            acc[mf] = __builtin_amdgcn_mfma_f32_16x16x32_bf16(al, bh, acc[mf], 0,0,0);
            acc[mf] = __builtin_amdgcn_mfma_f32_16x16x32_bf16(ah, bl, acc[mf], 0,0,0);
            acc[mf] = __builtin_amdgcn_mfma_f32_16x16x32_bf16(ah, bh, acc[mf], 0,0,0);
        }
    }
    // --- epilogue: D (o = mf*16+g*4+r, x = X0+xl)
    #pragma unroll
    for (int mf=0; mf<4; mf++){
        #pragma unroll
        for (int r=0; r<4; r++){
            int o = mf*16 + g*4 + r;
            float v = acc[mf][r] + skb[o];
            h32out[((size_t)(b*64 + o))*LL + X0 + xl] = pack_split(gelu_fast(v));
        }
    }
}

// ---------------- final: layer-3 tail at x=L-1 + projection ----------------
__global__ void k_final(const unsigned int* __restrict__ h32,
                        const float* __restrict__ of,
                        const float* __restrict__ skw, const float* __restrict__ skb,
                        const unsigned int* __restrict__ ti32,
                        const float* __restrict__ w1, const float* __restrict__ b1,
                        const float* __restrict__ w2, const float* __restrict__ b2,
                        float* __restrict__ out){
    int b = blockIdx.x;
    int tid = threadIdx.x;  // 128
    __shared__ float hch[64];
    __shared__ float til[64];
    __shared__ float hv[64];
    __shared__ float qv[128];
    if (tid < 64){
        hch[tid] = unpack_sum(h32[((size_t)(b*64 + tid))*LL + (LL-1)]);
    } else {
        til[tid-64] = unpack_sum(ti32[(size_t)(tid-64)*LL + (LL-1)]);
    }
    __syncthreads();
    if (tid < 64){
        int o = tid;
        float acc = skb[o];
        const float* ofr = of + ((size_t)b*WW + o)*64;
        #pragma unroll
        for (int j=0;j<64;j++) acc += ofr[j]*til[j];
        #pragma unroll
        for (int i=0;i<64;i++) acc += hch[i]*skw[i*64+o];
        hv[o] = acc;                       // last layer: no gelu
    }
    __syncthreads();
    {
        int p = tid;
        float acc = b1[p];
        for (int o=0;o<64;o++) acc += hv[o]*w1[o*NPROJ+p];
        qv[p] = gelu_fast(acc);
    }
    __syncthreads();
    if (tid < NSTC){
        int s = tid;
        float acc = b2[s];
        for (int p=0;p<NPROJ;p++) acc += qv[p]*w2[p*NSTC+s];
        out[b*NSTC + s] = acc;
    }
}

extern "C" void kernel_launch(void* const* d_in, const int* in_sizes, int n_in,
                              void* d_out, int out_size, void* d_ws, size_t ws_size,
                              hipStream_t stream) {
    const float* u     = (const float*)d_in[0];
    const float* z     = (const float*)d_in[1];
    // d_in[2] = t, unused by reference
    const float* fc0w  = (const float*)d_in[3];
    const float* fc0b  = (const float*)d_in[4];
    const float* swr   = (const float*)d_in[5];
    const float* swi   = (const float*)d_in[6];
    const float* skw   = (const float*)d_in[7];
    const float* skb   = (const float*)d_in[8];
    const float* fc1w  = (const float*)d_in[9];
    const float* fc1b  = (const float*)d_in[10];
    const float* fc2w  = (const float*)d_in[11];
    const float* fc2b  = (const float*)d_in[12];
    float* out = (float*)d_out;

    const size_t SZ_H    = (size_t)NB*WW*LL*4;          // 64 MiB per h32 buffer
    const size_t SZ_TBL  = (size_t)64*LL*4;             // 1 MiB per table
    const size_t SZ_HFT  = (size_t)64*32*128*4;         // 1 MiB
    const size_t SZ_OF   = (size_t)64*64*64*4;          // 1 MiB fp32
    const size_t SZ_OF32 = (size_t)64*64*64*4;          // 1 MiB packed
    const size_t SZ_WT   = (size_t)NLAY*NMODES*WW*WW*4; // 2 MiB
    const size_t SZ_SK32 = (size_t)NLAY*WW*WW*4;        // 64 KiB

    size_t need = 2*SZ_H + 2*SZ_TBL + SZ_HFT + SZ_OF + SZ_OF32 + 2*SZ_WT + SZ_SK32;
    if (ws_size < need) return;

    char* p = (char*)d_ws;
    unsigned int* hA32 = (unsigned int*)p; p += SZ_H;
    unsigned int* hB32 = (unsigned int*)p; p += SZ_H;
    unsigned int* TD32 = (unsigned int*)p; p += SZ_TBL;
    unsigned int* TI32 = (unsigned int*)p; p += SZ_TBL;
    float* hfT   = (float*)p; p += SZ_HFT;
    float* of    = (float*)p; p += SZ_OF;
    unsigned int* of32 = (unsigned int*)p; p += SZ_OF32;
    float* wrT   = (float*)p; p += SZ_WT;
    float* wiT   = (float*)p; p += SZ_WT;
    unsigned int* skw32 = (unsigned int*)p; p += SZ_SK32;

    k_tables<<<(LL*NMODES+255)/256, 256, 0, stream>>>(TD32, TI32);
    k_wt<<<(NLAY*WW*WW*NMODES+255)/256, 256, 0, stream>>>(swr, swi, wrT, wiT, skw, skw32);
    k_lift<<<dim3(LL/256, NB), 256, 0, stream>>>(u, z, fc0w, fc0b, hA32);

    unsigned int* cur = hA32;
    unsigned int* nxt = hB32;
    for (int l = 0; l < NLAY; l++){
        // part (16 MiB) aliases the dead destination buffer (64 MiB)
        float* part = (float*)nxt;
        k_dft<<<dim3(NB, NSPLIT), 256, 0, stream>>>(cur, TD32, part);
        k_reduce<<<(64*32*128)/256, 256, 0, stream>>>(part, hfT);
        k_mix<<<dim3(NMODES, NB), 64, 0, stream>>>(hfT, wrT + (size_t)l*NMODES*WW*WW,
                                                   wiT + (size_t)l*NMODES*WW*WW,
                                                   of, of32);
        if (l < NLAY-1){
            k_fused<<<dim3(LL/64, NB), 256, 0, stream>>>(cur, TI32,
                skw32 + (size_t)l*WW*WW, of32, skb + (size_t)l*WW, nxt);
            unsigned int* t = cur; cur = nxt; nxt = t;
        }
    }
    k_final<<<NB, 128, 0, stream>>>(cur, of, skw + (size_t)3*WW*WW,
                                    skb + (size_t)3*WW, TI32,
                                    fc1w, fc1b, fc2w, fc2b, out);
}